// Round 1
// baseline (1357.974 us; speedup 1.0000x reference)
//
#include <hip/hip_runtime.h>
#include <hip/hip_bf16.h>

#define IN_F 4096
#define OUT_F 4096
#define NNZ_CNT 4194304
#define NROWS 16384

typedef __attribute__((ext_vector_type(8))) __bf16 bf16x8;
typedef __attribute__((ext_vector_type(4))) float f32x4;

__device__ __forceinline__ unsigned short f2bf(float f) {
  unsigned int u = __float_as_uint(f);
  u += 0x7fff + ((u >> 16) & 1);  // round-to-nearest-even
  return (unsigned short)(u >> 16);
}

// ---------------- scatter: densify COO weight with summed duplicates ----------------
__global__ __launch_bounds__(256) void scatter_kernel(const int* __restrict__ rows,
                                                      const int* __restrict__ cols,
                                                      const float* __restrict__ vals,
                                                      float* __restrict__ W) {
  int i = blockIdx.x * blockDim.x + threadIdx.x;
  if (i < NNZ_CNT) atomicAdd(&W[rows[i] * IN_F + cols[i]], vals[i]);
}

// ---------------- fp32 -> bf16 convert, 4 elems/thread, grid-stride ----------------
__global__ __launch_bounds__(256) void cvt_kernel(const float* __restrict__ in,
                                                  unsigned short* __restrict__ out, int n4) {
  int i = blockIdx.x * blockDim.x + threadIdx.x;
  int stride = gridDim.x * blockDim.x;
  for (; i < n4; i += stride) {
    float4 a = ((const float4*)in)[i];
    ushort4 o;
    o.x = f2bf(a.x); o.y = f2bf(a.y); o.z = f2bf(a.z); o.w = f2bf(a.w);
    ((ushort4*)out)[i] = o;
  }
}

// ---------------- bf16 GEMM: C[M][N] = A[M][K] * B[N][K]^T  (m97 structure) ----------------
// 128x128 tile, BK=64, 256 threads (4 waves, 2x2 of 64x64), mfma_f32_16x16x32_bf16.
// LDS tiles [128][64] bf16, row stride 128B. XOR swizzle (row&7)<<4 on byte offset to kill
// the 16-way bank conflict; applied on the GLOBAL SOURCE for global_load_lds (linear dest)
// and on the ds_read address (G21: both-sides-or-neither).
__global__ __launch_bounds__(256) void gemm_bf16(const unsigned short* __restrict__ A,
                                                 const unsigned short* __restrict__ B,
                                                 float* __restrict__ C) {
  __shared__ __align__(16) unsigned char lds[2 * 128 * 64 * 2];  // 32 KiB: A then B
  unsigned char* ldsA = lds;
  unsigned char* ldsB = lds + 128 * 64 * 2;

  const int tid = threadIdx.x;
  const int lane = tid & 63;
  const int wave = tid >> 6;
  const int bn0 = blockIdx.x * 128;
  const int bm0 = blockIdx.y * 128;

  f32x4 acc[4][4] = {};

  // Staging coords: chunk c = r*256+tid indexes 16B units of the [128][64] tile.
  // row = c>>3 (8 chunks per row), c16 = c&7. Source chunk = c16 ^ (row&7)  (inverse swizzle).
  int srow[4], scol[4];
#pragma unroll
  for (int r = 0; r < 4; ++r) {
    int c = r * 256 + tid;
    int row = c >> 3, c16 = c & 7;
    srow[r] = row;
    scol[r] = (c16 ^ (row & 7)) * 8;  // element offset (8 bf16 = 16B per chunk)
  }

  const unsigned short* Abase = A + (long)bm0 * IN_F;
  const unsigned short* Bbase = B + (long)bn0 * IN_F;
  const int wm = (wave >> 1) * 64;
  const int wn = (wave & 1) * 64;

  for (int kt = 0; kt < IN_F / 64; ++kt) {
    __syncthreads();  // previous compute done before overwrite
    const unsigned short* Ak = Abase + kt * 64;
    const unsigned short* Bk = Bbase + kt * 64;
#pragma unroll
    for (int r = 0; r < 4; ++r) {
      __builtin_amdgcn_global_load_lds(
          (const __attribute__((address_space(1))) void*)(Ak + srow[r] * IN_F + scol[r]),
          (__attribute__((address_space(3))) void*)(ldsA + (r * 256 + tid) * 16), 16, 0, 0);
    }
#pragma unroll
    for (int r = 0; r < 4; ++r) {
      __builtin_amdgcn_global_load_lds(
          (const __attribute__((address_space(1))) void*)(Bk + srow[r] * IN_F + scol[r]),
          (__attribute__((address_space(3))) void*)(ldsB + (r * 256 + tid) * 16), 16, 0, 0);
    }
    __syncthreads();  // compiler emits vmcnt(0) drain here

#pragma unroll
    for (int kk2 = 0; kk2 < 2; ++kk2) {
      const int colbyte = (kk2 * 32 + (lane >> 4) * 8) * 2;
      bf16x8 a[4], b[4];
#pragma unroll
      for (int mi = 0; mi < 4; ++mi) {
        int row = wm + mi * 16 + (lane & 15);
        a[mi] = *(const bf16x8*)(ldsA + row * 128 + (colbyte ^ ((row & 7) << 4)));
      }
#pragma unroll
      for (int ni = 0; ni < 4; ++ni) {
        int row = wn + ni * 16 + (lane & 15);
        b[ni] = *(const bf16x8*)(ldsB + row * 128 + (colbyte ^ ((row & 7) << 4)));
      }
#pragma unroll
      for (int mi = 0; mi < 4; ++mi)
#pragma unroll
        for (int ni = 0; ni < 4; ++ni)
          acc[mi][ni] = __builtin_amdgcn_mfma_f32_16x16x32_bf16(a[mi], b[ni], acc[mi][ni], 0, 0, 0);
    }
  }

  // Epilogue: C/D layout col=lane&15, row=(lane>>4)*4+reg  [measured m89]
  const int crow0 = bm0 + wm + (lane >> 4) * 4;
  const int ccol0 = bn0 + wn + (lane & 15);
#pragma unroll
  for (int mi = 0; mi < 4; ++mi)
#pragma unroll
    for (int ni = 0; ni < 4; ++ni)
#pragma unroll
      for (int r = 0; r < 4; ++r)
        C[(long)(crow0 + mi * 16 + r) * OUT_F + ccol0 + ni * 16] = acc[mi][ni][r];
}

// ---------------- fp32 fallback GEMM (insurance if ws too small for bf16 path) ----------------
__global__ __launch_bounds__(256) void gemm_f32_fb(const float* __restrict__ A,
                                                   const float* __restrict__ B,
                                                   float* __restrict__ C) {
  __shared__ float As[16][64], Bs[16][64];
  int tid = threadIdx.x;
  int bm0 = blockIdx.y * 64, bn0 = blockIdx.x * 64;
  int tx = tid & 15, ty = tid >> 4;
  float acc[4][4] = {};
  for (int k0 = 0; k0 < IN_F; k0 += 16) {
    __syncthreads();
#pragma unroll
    for (int r = 0; r < 4; ++r) {
      int e = r * 256 + tid;  // [0,1024): row=e>>4, col=e&15
      As[e & 15][e >> 4] = A[(long)(bm0 + (e >> 4)) * IN_F + k0 + (e & 15)];
      Bs[e & 15][e >> 4] = B[(long)(bn0 + (e >> 4)) * IN_F + k0 + (e & 15)];
    }
    __syncthreads();
#pragma unroll
    for (int kk = 0; kk < 16; ++kk)
#pragma unroll
      for (int i = 0; i < 4; ++i)
#pragma unroll
        for (int j = 0; j < 4; ++j)
          acc[i][j] += As[kk][ty * 4 + i] * Bs[kk][tx * 4 + j];
  }
#pragma unroll
  for (int i = 0; i < 4; ++i)
#pragma unroll
    for (int j = 0; j < 4; ++j)
      C[(long)(bm0 + ty * 4 + i) * OUT_F + bn0 + tx * 4 + j] = acc[i][j];
}

extern "C" void kernel_launch(void* const* d_in, const int* in_sizes, int n_in,
                              void* d_out, int out_size, void* d_ws, size_t ws_size,
                              hipStream_t stream) {
  const float* x = (const float*)d_in[0];
  const int* rows = (const int*)d_in[1];
  const int* cols = (const int*)d_in[2];
  const float* vals = (const float*)d_in[3];
  float* out = (float*)d_out;

  const size_t W32_BYTES = (size_t)OUT_F * IN_F * 4;   // 64 MiB
  const size_t WBF_BYTES = (size_t)OUT_F * IN_F * 2;   // 32 MiB
  const size_t XBF_BYTES = (size_t)NROWS * IN_F * 2;   // 128 MiB

  float* Wf = (float*)d_ws;
  hipMemsetAsync(Wf, 0, W32_BYTES, stream);
  scatter_kernel<<<NNZ_CNT / 256, 256, 0, stream>>>(rows, cols, vals, Wf);

  if (ws_size >= W32_BYTES + WBF_BYTES + XBF_BYTES) {
    unsigned short* Wbf = (unsigned short*)((char*)d_ws + W32_BYTES);
    unsigned short* xbf = (unsigned short*)((char*)d_ws + W32_BYTES + WBF_BYTES);
    cvt_kernel<<<4096, 256, 0, stream>>>((const float*)Wf, Wbf, OUT_F * IN_F / 4);
    cvt_kernel<<<8192, 256, 0, stream>>>(x, xbf, NROWS * IN_F / 4);
    dim3 grid(OUT_F / 128, NROWS / 128);
    gemm_bf16<<<grid, 256, 0, stream>>>(xbf, Wbf, out);
  } else {
    dim3 grid(OUT_F / 64, NROWS / 64);
    gemm_f32_fb<<<grid, 256, 0, stream>>>(x, Wf, out);
  }
}